// Round 10
// baseline (344.917 us; speedup 1.0000x reference)
//
#include <hip/hip_runtime.h>
#include <hip/hip_bf16.h>
#include <stdint.h>

#define CHUNKC 32
#define PRIORC 64
#define POSEC 512
#define PREDC 128
#define NB 2048
#define K1 (CHUNKC*POSEC)   // 16384
#define KS 16               // split-K factor (bf16 partials)
#define KCH (K1/KS)         // 1024

typedef __attribute__((ext_vector_type(8))) short bf16x8;
typedef __attribute__((ext_vector_type(8))) unsigned short u16x8;
typedef __attribute__((ext_vector_type(4))) float f32x4;
typedef __attribute__((ext_vector_type(4))) float f4v;
typedef __attribute__((ext_vector_type(4))) unsigned short u16x4;

__device__ __forceinline__ unsigned short f2b(float f) {
    union { float f; unsigned int u; } x; x.f = f;
    unsigned int r = x.u + 0x7fffu + ((x.u >> 16) & 1u);
    return (unsigned short)(r >> 16);
}
__device__ __forceinline__ float b2f(unsigned short u) {
    union { unsigned int i; float f; } x; x.i = ((unsigned int)u) << 16; return x.f;
}

__device__ __forceinline__ void gload_lds16(const void* g, void* l) {
    __builtin_amdgcn_global_load_lds(
        (const __attribute__((address_space(1))) unsigned int*)g,
        (__attribute__((address_space(3))) unsigned int*)l, 16, 0, 0);
}

// ---------------- cvt_all: x-slice, W1, W2 -> bf16 (nontemporal streams) ----------------
#define XN4   8388608   // 2048*4096 float4 of x-slice
#define W1N4  2097152   // 512*16384/4
#define W2N4  65536     // 512*512/4
__global__ __launch_bounds__(256) void cvt_all_kernel(const f4v* __restrict__ init,
                                                      const f4v* __restrict__ W1,
                                                      const f4v* __restrict__ W2,
                                                      u16x4* __restrict__ xb,
                                                      u16x4* __restrict__ w1b,
                                                      u16x4* __restrict__ w2b) {
    const int64_t n = XN4 + W1N4 + W2N4;
    const int64_t stride = (int64_t)gridDim.x * blockDim.x;
    for (int64_t i = (int64_t)blockIdx.x * blockDim.x + threadIdx.x; i < n; i += stride) {
        f4v v; u16x4* dst;
        if (i < XN4) {
            int64_t b = i >> 12, r = i & 4095;
            v = __builtin_nontemporal_load(init + b * 8192 + 4096 + r);
            dst = xb + i;
        } else if (i < XN4 + W1N4) {
            v = __builtin_nontemporal_load(W1 + (i - XN4));
            dst = w1b + (i - XN4);
        } else {
            v = __builtin_nontemporal_load(W2 + (i - XN4 - W1N4));
            dst = w2b + (i - XN4 - W1N4);
        }
        u16x4 o;
        o[0] = f2b(v[0]); o[1] = f2b(v[1]); o[2] = f2b(v[2]); o[3] = f2b(v[3]);
        __builtin_nontemporal_store(o, dst);
    }
}

// ---------------- GEMM1: bf16 partials of x @ W1^T ----------------
// 128x128 tile, BK=64, 4 waves (2x2; wave owns 64x64), gload_lds both operands.
// 2-phase dbuf + T2 XOR-swizzle; LDS 64 KB -> 2 blocks/CU (inter-block overlap
// hides the barrier drain, m114). grid = 16 mt * 4 nt * 16 ks = 1024 blocks;
// XCD-chunked bijective swizzle (each XCD: all mt/nt, 2 ks layers -> B L2-hot).
__global__ __launch_bounds__(256) void gemm1_kernel(const ushort* __restrict__ xb,
                                                    const ushort* __restrict__ w1b,
                                                    ushort* __restrict__ part) {
    __shared__ ushort As[2][128][64];   // 2 x 16 KB
    __shared__ ushort Bs[2][128][64];   // 2 x 16 KB
    const int t = threadIdx.x;
    const int l = t & 63, wid = t >> 6;
    const int wr = wid >> 1, wc = wid & 1;          // 2x2 waves; wave owns 64x64
    const int cpx = 1024 >> 3;                      // 128 blocks per XCD chunk
    const int orig = (blockIdx.x & 7) * cpx + (blockIdx.x >> 3);
    const int mt = orig & 15, nt = (orig >> 4) & 3, ks = orig >> 6;
    const int NIT = KCH / 64;                       // 16

    f32x4 acc[4][4] = {};

    const ushort* aG = xb  + (int64_t)(mt * 128) * K1 + ks * KCH;
    const ushort* bG = w1b + (int64_t)(nt * 128) * K1 + ks * KCH;
    const int srow = t >> 3;                        // 0..31 within a 32-row chunk
    // T2: source col-slot XORed with dest-row&7 ( == (t>>3)&7 ); dest stays lane-linear
    const int scol = (((t & 7) ^ ((t >> 3) & 7))) * 8;

    const int fr = l & 15, fq = l >> 4;
    const int cx = fr & 7;                          // read-side swizzle key

    // prologue: stage tile 0 into buffer 0 (4 chunks of 32 rows, A and B)
#pragma unroll
    for (int i = 0; i < 4; ++i) {
        gload_lds16(aG + (int64_t)(i * 32 + srow) * K1 + scol,
                    (char*)&As[0][0][0] + i * 4096 + wid * 1024);
        gload_lds16(bG + (int64_t)(i * 32 + srow) * K1 + scol,
                    (char*)&Bs[0][0][0] + i * 4096 + wid * 1024);
    }

    for (int it = 0; it < NIT; ++it) {
        const int cur = it & 1;
        __syncthreads();    // drains buf[cur]'s loads (issued one full iter ago)
        if (it + 1 < NIT) {
            const int nxt = cur ^ 1;
            const int k0 = (it + 1) * 64;
#pragma unroll
            for (int i = 0; i < 4; ++i) {
                gload_lds16(aG + (int64_t)(i * 32 + srow) * K1 + k0 + scol,
                            (char*)&As[nxt][0][0] + i * 4096 + wid * 1024);
                gload_lds16(bG + (int64_t)(i * 32 + srow) * K1 + k0 + scol,
                            (char*)&Bs[nxt][0][0] + i * 4096 + wid * 1024);
            }
        }
#pragma unroll
        for (int k2 = 0; k2 < 2; ++k2) {
            const int cs = ((k2 * 4 + fq) ^ cx) * 8;    // swizzled col byte-slot
            bf16x8 a[4], b[4];
#pragma unroll
            for (int m = 0; m < 4; ++m)
                a[m] = *(const bf16x8*)&As[cur][wr * 64 + m * 16 + fr][cs];
#pragma unroll
            for (int n = 0; n < 4; ++n)
                b[n] = *(const bf16x8*)&Bs[cur][wc * 64 + n * 16 + fr][cs];
#pragma unroll
            for (int m = 0; m < 4; ++m)
#pragma unroll
                for (int n = 0; n < 4; ++n)
                    acc[m][n] = __builtin_amdgcn_mfma_f32_16x16x32_bf16(a[m], b[n], acc[m][n], 0, 0, 0);
        }
    }

    ushort* P = part + (int64_t)ks * NB * POSEC;
    const int mbase = mt * 128 + wr * 64, nbase = nt * 128 + wc * 64;
#pragma unroll
    for (int m = 0; m < 4; ++m)
#pragma unroll
        for (int n = 0; n < 4; ++n) {
            int row0 = mbase + m * 16 + fq * 4;
            int col  = nbase + n * 16 + fr;
#pragma unroll
            for (int r = 0; r < 4; ++r)
                P[(int64_t)(row0 + r) * POSEC + col] = f2b(acc[m][n][r]);
        }
}

// ---------------- reduce: A2 = bf16(sum_ks bf16part + b1) ----------------
__global__ __launch_bounds__(256) void reduce_kernel(const ushort* __restrict__ part,
                                                     const float* __restrict__ b1,
                                                     u16x8* __restrict__ A2) {
    const int gid = blockIdx.x * 256 + threadIdx.x;     // 131072 threads, 8 elems each
    const int64_t e0 = (int64_t)gid * 8;
    float s[8] = {};
#pragma unroll
    for (int k = 0; k < KS; ++k) {
        u16x8 p = *(const u16x8*)(part + (int64_t)k * (NB * POSEC) + e0);
#pragma unroll
        for (int j = 0; j < 8; ++j) s[j] += b2f(p[j]);
    }
    const int col = (int)(e0 & 511);
    f4v b0 = *(const f4v*)&b1[col];
    f4v b4 = *(const f4v*)&b1[col + 4];
    u16x8 o;
#pragma unroll
    for (int j = 0; j < 4; ++j) { o[j] = f2b(s[j] + b0[j]); o[j+4] = f2b(s[j+4] + b4[j]); }
    A2[gid] = o;
}

// ---------------- GEMM2: mem = A2 @ W2b^T + b2 (swizzled, round-9) ----------------
__global__ __launch_bounds__(256) void gemm2_kernel(const ushort* __restrict__ A2,
                                                    const ushort* __restrict__ w2b,
                                                    const float* __restrict__ b2,
                                                    float* __restrict__ mem) {
    __shared__ ushort As[64][64];
    __shared__ ushort Bs[64][64];
    const int t = threadIdx.x;
    const int l = t & 63, wid = t >> 6;
    const int wr = wid >> 1, wc = wid & 1;
    const int mt = blockIdx.x >> 3, nt = blockIdx.x & 7;

    f32x4 acc[2][2] = {};
    const ushort* aG = A2  + (int64_t)(mt * 64) * POSEC;
    const ushort* bG = w2b + (int64_t)(nt * 64) * POSEC;
    const int srow = t >> 3;
    const int scol = (((t & 7) ^ ((t >> 3) & 7))) * 8;
    const int fr = l & 15, fq = l >> 4;
    const int cx = fr & 7;

    for (int k0 = 0; k0 < POSEC; k0 += 64) {
#pragma unroll
        for (int i = 0; i < 2; ++i) {
            gload_lds16(aG + (int64_t)(i * 32 + srow) * POSEC + k0 + scol,
                        (char*)&As[0][0] + i * 4096 + wid * 1024);
            gload_lds16(bG + (int64_t)(i * 32 + srow) * POSEC + k0 + scol,
                        (char*)&Bs[0][0] + i * 4096 + wid * 1024);
        }
        __syncthreads();
#pragma unroll
        for (int k2 = 0; k2 < 2; ++k2) {
            const int cs = ((k2 * 4 + fq) ^ cx) * 8;
            bf16x8 a[2], b[2];
#pragma unroll
            for (int m = 0; m < 2; ++m)
                a[m] = *(const bf16x8*)&As[wr * 32 + m * 16 + fr][cs];
#pragma unroll
            for (int n = 0; n < 2; ++n)
                b[n] = *(const bf16x8*)&Bs[wc * 32 + n * 16 + fr][cs];
#pragma unroll
            for (int m = 0; m < 2; ++m)
#pragma unroll
                for (int n = 0; n < 2; ++n)
                    acc[m][n] = __builtin_amdgcn_mfma_f32_16x16x32_bf16(a[m], b[n], acc[m][n], 0, 0, 0);
        }
        __syncthreads();
    }

    const int mbase = mt * 64 + wr * 32, nbase = nt * 64 + wc * 32;
#pragma unroll
    for (int m = 0; m < 2; ++m)
#pragma unroll
        for (int n = 0; n < 2; ++n) {
            int row0 = mbase + m * 16 + fq * 4;
            int col  = nbase + n * 16 + fr;
            float bias = b2[col];
#pragma unroll
            for (int r = 0; r < 4; ++r)
                mem[(int64_t)(row0 + r) * POSEC + col] = acc[m][n][r] + bias;
        }
}

// ---------------- score + sigmoid + blend + copy (round-2 + nt tail) ----------------
__global__ __launch_bounds__(256) void blend_kernel(const float* __restrict__ pred,
                                                    const float* __restrict__ mem,
                                                    float* __restrict__ out) {
    const int b = blockIdx.x;
    const int t = threadIdx.x;
    __shared__ float sm[POSEC];
    __shared__ float sg[CHUNKC];

    sm[t]       = mem[(int64_t)b * POSEC + t];
    sm[t + 256] = mem[(int64_t)b * POSEC + 256 + t];
    __syncthreads();

    const int l = t & 63, wid = t >> 6;
    const float4* sm4 = (const float4*)sm;
    const float4* p4 = (const float4*)pred + (int64_t)b * 16384;
    float4* o4 = (float4*)out + (int64_t)b * 16384;

#pragma unroll
    for (int ci = 0; ci < 8; ++ci) {
        int c = wid * 8 + ci;
        float4 h0 = p4[c * 128 + l * 2];
        float4 h1 = p4[c * 128 + l * 2 + 1];
        float4 m0 = sm4[l * 2];
        float4 m1 = sm4[l * 2 + 1];
        float s = h0.x * m0.x + h0.y * m0.y + h0.z * m0.z + h0.w * m0.w
                + h1.x * m1.x + h1.y * m1.y + h1.z * m1.z + h1.w * m1.w;
#pragma unroll
        for (int o = 32; o; o >>= 1) s += __shfl_xor(s, o);
        if (l == 0) sg[c] = 1.0f / (1.0f + expf(-s));
    }
    __syncthreads();

#pragma unroll
    for (int i = 0; i < 16; ++i) {
        int idx = i * 256 + t;
        int row = idx >> 7, c4 = idx & 127;
        float g = sg[row];
        float4 h = p4[idx];
        float4 m = sm4[c4];
        float4 r;
        r.x = g * h.x + (1.0f - g) * m.x;
        r.y = g * h.y + (1.0f - g) * m.y;
        r.z = g * h.z + (1.0f - g) * m.z;
        r.w = g * h.w + (1.0f - g) * m.w;
        o4[idx] = r;
    }
#pragma unroll
    for (int i = 0; i < 48; ++i) {
        int idx = 4096 + i * 256 + t;
        f4v h = __builtin_nontemporal_load((const f4v*)p4 + idx);
        __builtin_nontemporal_store(h, (f4v*)o4 + idx);
    }
}

// ---------------- launch ----------------

extern "C" void kernel_launch(void* const* d_in, const int* in_sizes, int n_in,
                              void* d_out, int out_size, void* d_ws, size_t ws_size,
                              hipStream_t stream) {
    const float* init = (const float*)d_in[0];
    const float* pred = (const float*)d_in[1];
    const float* W1   = (const float*)d_in[2];
    const float* b1   = (const float*)d_in[3];
    const float* W2   = (const float*)d_in[4];
    const float* b2   = (const float*)d_in[5];
    float* out = (float*)d_out;

    char* ws = (char*)d_ws;
    ushort* xb   = (ushort*)(ws);                       // 67108864 B
    ushort* w1b  = (ushort*)(ws + 67108864);            // 16777216 B
    ushort* w2b  = (ushort*)(ws + 83886080);            //   524288 B
    ushort* part = (ushort*)(ws + 84410368);            // 33554432 B (16 x 2048x512 bf16)
    ushort* A2   = (ushort*)(ws + 117964800);           //  2097152 B
    float*  mem  = (float*) (ws + 120061952);           //  4194304 B
    // total 124,256,256 B == proven footprint

    cvt_all_kernel<<<2560, 256, 0, stream>>>((const f4v*)init, (const f4v*)W1,
                                             (const f4v*)W2,
                                             (u16x4*)xb, (u16x4*)w1b, (u16x4*)w2b);
    gemm1_kernel<<<1024, 256, 0, stream>>>(xb, w1b, part);
    reduce_kernel<<<512, 256, 0, stream>>>(part, b1, (u16x8*)A2);
    gemm2_kernel<<<256, 256, 0, stream>>>(A2, w2b, b2, mem);
    blend_kernel<<<NB, 256, 0, stream>>>(pred, mem, out);
}

// Round 11
// 319.723 us; speedup vs baseline: 1.0788x; 1.0788x over previous
//
#include <hip/hip_runtime.h>
#include <hip/hip_bf16.h>
#include <stdint.h>

#define CHUNKC 32
#define PRIORC 64
#define POSEC 512
#define PREDC 128
#define NB 2048
#define K1 (CHUNKC*POSEC)   // 16384
#define KS 16               // split-K factor (bf16 partials)
#define KCH (K1/KS)         // 1024

typedef __attribute__((ext_vector_type(8))) short bf16x8;
typedef __attribute__((ext_vector_type(8))) unsigned short u16x8;
typedef __attribute__((ext_vector_type(4))) float f32x4;
typedef __attribute__((ext_vector_type(4))) float f4v;
typedef __attribute__((ext_vector_type(4))) unsigned short u16x4;

__device__ __forceinline__ unsigned short f2b(float f) {
    union { float f; unsigned int u; } x; x.f = f;
    unsigned int r = x.u + 0x7fffu + ((x.u >> 16) & 1u);
    return (unsigned short)(r >> 16);
}
__device__ __forceinline__ float b2f(unsigned short u) {
    union { unsigned int i; float f; } x; x.i = ((unsigned int)u) << 16; return x.f;
}

__device__ __forceinline__ void gload_lds16(const void* g, void* l) {
    __builtin_amdgcn_global_load_lds(
        (const __attribute__((address_space(1))) unsigned int*)g,
        (__attribute__((address_space(3))) unsigned int*)l, 16, 0, 0);
}

// ---------------- cvt_all: x-slice, W1, W2 -> bf16 ----------------
// PLAIN loads/stores (NO nontemporal): outputs xb/w1b/w2b are RE-READ by the
// GEMMs and must stay L2/L3-resident. (Round-6's nt stores evicted them ->
// gemm1 staged from HBM at full latency; that was the hidden ~35 us tax.)
#define XN4   8388608   // 2048*4096 float4 of x-slice
#define W1N4  2097152   // 512*16384/4
#define W2N4  65536     // 512*512/4
__global__ __launch_bounds__(256) void cvt_all_kernel(const float4* __restrict__ init,
                                                      const float4* __restrict__ W1,
                                                      const float4* __restrict__ W2,
                                                      ushort4* __restrict__ xb,
                                                      ushort4* __restrict__ w1b,
                                                      ushort4* __restrict__ w2b) {
    const int64_t n = XN4 + W1N4 + W2N4;
    const int64_t stride = (int64_t)gridDim.x * blockDim.x;
    for (int64_t i = (int64_t)blockIdx.x * blockDim.x + threadIdx.x; i < n; i += stride) {
        float4 v; ushort4* dst;
        if (i < XN4) {
            int64_t b = i >> 12, r = i & 4095;
            v = init[b * 8192 + 4096 + r];
            dst = xb + i;
        } else if (i < XN4 + W1N4) {
            v = W1[i - XN4];
            dst = w1b + (i - XN4);
        } else {
            v = W2[i - XN4 - W1N4];
            dst = w2b + (i - XN4 - W1N4);
        }
        *dst = make_ushort4(f2b(v.x), f2b(v.y), f2b(v.z), f2b(v.w));
    }
}

// ---------------- GEMM1: bf16 partials of x @ W1^T (round-9 proven) ----------------
// 256x256 tile, BK=64, 8 waves (2x4; wave owns 128x64), gload_lds both operands.
// 2-phase dbuf + T2 XOR-swizzle (linear LDS dest, inverse-swizzled global source
// col-slot, swizzled read col-slot). grid = 8mt*2nt*16ks = 256; XCD-chunked swizzle.
__global__ __launch_bounds__(512) void gemm1_kernel(const ushort* __restrict__ xb,
                                                    const ushort* __restrict__ w1b,
                                                    ushort* __restrict__ part) {
    __shared__ ushort As[2][256][64];   // 2 x 32 KB
    __shared__ ushort Bs[2][256][64];   // 2 x 32 KB
    const int t = threadIdx.x;
    const int l = t & 63, wid = t >> 6;
    const int wr = wid >> 2, wc = wid & 3;          // 2x4 waves; wave owns 128x64
    const int cpx = 256 >> 3;
    const int orig = (blockIdx.x & 7) * cpx + (blockIdx.x >> 3);
    const int mt = orig & 7, nt = (orig >> 3) & 1, ks = orig >> 4;
    const int NIT = KCH / 64;                       // 16

    f32x4 acc[8][4] = {};

    const ushort* aG = xb  + (int64_t)(mt * 256) * K1 + ks * KCH;
    const ushort* bG = w1b + (int64_t)(nt * 256) * K1 + ks * KCH;
    const int srow = t >> 3;
    const int scol = (((t & 7) ^ ((t >> 3) & 7))) * 8;

    const int fr = l & 15, fq = l >> 4;
    const int cx = fr & 7;                          // read-side swizzle key

    // prologue: stage tile 0 into buffer 0
#pragma unroll
    for (int i = 0; i < 4; ++i) {
        gload_lds16(aG + (int64_t)(i * 64 + srow) * K1 + scol,
                    (char*)&As[0][0][0] + i * 8192 + wid * 1024);
        gload_lds16(bG + (int64_t)(i * 64 + srow) * K1 + scol,
                    (char*)&Bs[0][0][0] + i * 8192 + wid * 1024);
    }

    for (int it = 0; it < NIT; ++it) {
        const int cur = it & 1;
        __syncthreads();    // drains buf[cur]'s loads (issued one full iter ago)
        if (it + 1 < NIT) {
            const int nxt = cur ^ 1;
            const int k0 = (it + 1) * 64;
#pragma unroll
            for (int i = 0; i < 4; ++i) {
                gload_lds16(aG + (int64_t)(i * 64 + srow) * K1 + k0 + scol,
                            (char*)&As[nxt][0][0] + i * 8192 + wid * 1024);
                gload_lds16(bG + (int64_t)(i * 64 + srow) * K1 + k0 + scol,
                            (char*)&Bs[nxt][0][0] + i * 8192 + wid * 1024);
            }
        }
#pragma unroll
        for (int k2 = 0; k2 < 2; ++k2) {
            const int cs = ((k2 * 4 + fq) ^ cx) * 8;    // swizzled col byte-slot
            bf16x8 a[8], b[4];
#pragma unroll
            for (int m = 0; m < 8; ++m)
                a[m] = *(const bf16x8*)&As[cur][wr * 128 + m * 16 + fr][cs];
#pragma unroll
            for (int n = 0; n < 4; ++n)
                b[n] = *(const bf16x8*)&Bs[cur][wc * 64 + n * 16 + fr][cs];
#pragma unroll
            for (int m = 0; m < 8; ++m)
#pragma unroll
                for (int n = 0; n < 4; ++n)
                    acc[m][n] = __builtin_amdgcn_mfma_f32_16x16x32_bf16(a[m], b[n], acc[m][n], 0, 0, 0);
        }
    }

    ushort* P = part + (int64_t)ks * NB * POSEC;
    const int mbase = mt * 256 + wr * 128, nbase = nt * 256 + wc * 64;
#pragma unroll
    for (int m = 0; m < 8; ++m)
#pragma unroll
        for (int n = 0; n < 4; ++n) {
            int row0 = mbase + m * 16 + fq * 4;
            int col  = nbase + n * 16 + fr;
#pragma unroll
            for (int r = 0; r < 4; ++r)
                P[(int64_t)(row0 + r) * POSEC + col] = f2b(acc[m][n][r]);
        }
}

// ---------------- reduce: A2 = bf16(sum_ks bf16part + b1) ----------------
__global__ __launch_bounds__(256) void reduce_kernel(const ushort* __restrict__ part,
                                                     const float* __restrict__ b1,
                                                     u16x8* __restrict__ A2) {
    const int gid = blockIdx.x * 256 + threadIdx.x;     // 131072 threads, 8 elems each
    const int64_t e0 = (int64_t)gid * 8;
    float s[8] = {};
#pragma unroll
    for (int k = 0; k < KS; ++k) {
        u16x8 p = *(const u16x8*)(part + (int64_t)k * (NB * POSEC) + e0);
#pragma unroll
        for (int j = 0; j < 8; ++j) s[j] += b2f(p[j]);
    }
    const int col = (int)(e0 & 511);
    f4v b0 = *(const f4v*)&b1[col];
    f4v b4 = *(const f4v*)&b1[col + 4];
    u16x8 o;
#pragma unroll
    for (int j = 0; j < 4; ++j) { o[j] = f2b(s[j] + b0[j]); o[j+4] = f2b(s[j+4] + b4[j]); }
    A2[gid] = o;
}

// ---------------- GEMM2: mem = A2 @ W2b^T + b2 (swizzled, round-9) ----------------
__global__ __launch_bounds__(256) void gemm2_kernel(const ushort* __restrict__ A2,
                                                    const ushort* __restrict__ w2b,
                                                    const float* __restrict__ b2,
                                                    float* __restrict__ mem) {
    __shared__ ushort As[64][64];
    __shared__ ushort Bs[64][64];
    const int t = threadIdx.x;
    const int l = t & 63, wid = t >> 6;
    const int wr = wid >> 1, wc = wid & 1;
    const int mt = blockIdx.x >> 3, nt = blockIdx.x & 7;

    f32x4 acc[2][2] = {};
    const ushort* aG = A2  + (int64_t)(mt * 64) * POSEC;
    const ushort* bG = w2b + (int64_t)(nt * 64) * POSEC;
    const int srow = t >> 3;
    const int scol = (((t & 7) ^ ((t >> 3) & 7))) * 8;
    const int fr = l & 15, fq = l >> 4;
    const int cx = fr & 7;

    for (int k0 = 0; k0 < POSEC; k0 += 64) {
#pragma unroll
        for (int i = 0; i < 2; ++i) {
            gload_lds16(aG + (int64_t)(i * 32 + srow) * POSEC + k0 + scol,
                        (char*)&As[0][0] + i * 4096 + wid * 1024);
            gload_lds16(bG + (int64_t)(i * 32 + srow) * POSEC + k0 + scol,
                        (char*)&Bs[0][0] + i * 4096 + wid * 1024);
        }
        __syncthreads();
#pragma unroll
        for (int k2 = 0; k2 < 2; ++k2) {
            const int cs = ((k2 * 4 + fq) ^ cx) * 8;
            bf16x8 a[2], b[2];
#pragma unroll
            for (int m = 0; m < 2; ++m)
                a[m] = *(const bf16x8*)&As[wr * 32 + m * 16 + fr][cs];
#pragma unroll
            for (int n = 0; n < 2; ++n)
                b[n] = *(const bf16x8*)&Bs[wc * 32 + n * 16 + fr][cs];
#pragma unroll
            for (int m = 0; m < 2; ++m)
#pragma unroll
                for (int n = 0; n < 2; ++n)
                    acc[m][n] = __builtin_amdgcn_mfma_f32_16x16x32_bf16(a[m], b[n], acc[m][n], 0, 0, 0);
        }
        __syncthreads();
    }

    const int mbase = mt * 64 + wr * 32, nbase = nt * 64 + wc * 32;
#pragma unroll
    for (int m = 0; m < 2; ++m)
#pragma unroll
        for (int n = 0; n < 2; ++n) {
            int row0 = mbase + m * 16 + fq * 4;
            int col  = nbase + n * 16 + fr;
            float bias = b2[col];
#pragma unroll
            for (int r = 0; r < 4; ++r)
                mem[(int64_t)(row0 + r) * POSEC + col] = acc[m][n][r] + bias;
        }
}

// ---------------- score + sigmoid + blend + copy (nt only on one-touch tail) ----------------
__global__ __launch_bounds__(256) void blend_kernel(const float* __restrict__ pred,
                                                    const float* __restrict__ mem,
                                                    float* __restrict__ out) {
    const int b = blockIdx.x;
    const int t = threadIdx.x;
    __shared__ float sm[POSEC];
    __shared__ float sg[CHUNKC];

    sm[t]       = mem[(int64_t)b * POSEC + t];
    sm[t + 256] = mem[(int64_t)b * POSEC + 256 + t];
    __syncthreads();

    const int l = t & 63, wid = t >> 6;
    const float4* sm4 = (const float4*)sm;
    const float4* p4 = (const float4*)pred + (int64_t)b * 16384;
    float4* o4 = (float4*)out + (int64_t)b * 16384;

#pragma unroll
    for (int ci = 0; ci < 8; ++ci) {
        int c = wid * 8 + ci;
        float4 h0 = p4[c * 128 + l * 2];
        float4 h1 = p4[c * 128 + l * 2 + 1];
        float4 m0 = sm4[l * 2];
        float4 m1 = sm4[l * 2 + 1];
        float s = h0.x * m0.x + h0.y * m0.y + h0.z * m0.z + h0.w * m0.w
                + h1.x * m1.x + h1.y * m1.y + h1.z * m1.z + h1.w * m1.w;
#pragma unroll
        for (int o = 32; o; o >>= 1) s += __shfl_xor(s, o);
        if (l == 0) sg[c] = 1.0f / (1.0f + expf(-s));
    }
    __syncthreads();

#pragma unroll
    for (int i = 0; i < 16; ++i) {
        int idx = i * 256 + t;
        int row = idx >> 7, c4 = idx & 127;
        float g = sg[row];
        float4 h = p4[idx];
        float4 m = sm4[c4];
        float4 r;
        r.x = g * h.x + (1.0f - g) * m.x;
        r.y = g * h.y + (1.0f - g) * m.y;
        r.z = g * h.z + (1.0f - g) * m.z;
        r.w = g * h.w + (1.0f - g) * m.w;
        o4[idx] = r;
    }
#pragma unroll
    for (int i = 0; i < 48; ++i) {
        int idx = 4096 + i * 256 + t;
        f4v h = __builtin_nontemporal_load((const f4v*)p4 + idx);
        __builtin_nontemporal_store(h, (f4v*)o4 + idx);
    }
}

// ---------------- launch ----------------

extern "C" void kernel_launch(void* const* d_in, const int* in_sizes, int n_in,
                              void* d_out, int out_size, void* d_ws, size_t ws_size,
                              hipStream_t stream) {
    const float* init = (const float*)d_in[0];
    const float* pred = (const float*)d_in[1];
    const float* W1   = (const float*)d_in[2];
    const float* b1   = (const float*)d_in[3];
    const float* W2   = (const float*)d_in[4];
    const float* b2   = (const float*)d_in[5];
    float* out = (float*)d_out;

    char* ws = (char*)d_ws;
    ushort* xb   = (ushort*)(ws);                       // 67108864 B
    ushort* w1b  = (ushort*)(ws + 67108864);            // 16777216 B
    ushort* w2b  = (ushort*)(ws + 83886080);            //   524288 B
    ushort* part = (ushort*)(ws + 84410368);            // 33554432 B (16 x 2048x512 bf16)
    ushort* A2   = (ushort*)(ws + 117964800);           //  2097152 B
    float*  mem  = (float*) (ws + 120061952);           //  4194304 B
    // total 124,256,256 B == proven footprint

    cvt_all_kernel<<<2560, 256, 0, stream>>>((const float4*)init, (const float4*)W1,
                                             (const float4*)W2,
                                             (ushort4*)xb, (ushort4*)w1b, (ushort4*)w2b);
    gemm1_kernel<<<256, 512, 0, stream>>>(xb, w1b, part);
    reduce_kernel<<<512, 256, 0, stream>>>(part, b1, (u16x8*)A2);
    gemm2_kernel<<<256, 256, 0, stream>>>(A2, w2b, b2, mem);
    blend_kernel<<<NB, 256, 0, stream>>>(pred, mem, out);
}

// Round 12
// 295.528 us; speedup vs baseline: 1.1671x; 1.0819x over previous
//
#include <hip/hip_runtime.h>
#include <hip/hip_bf16.h>
#include <stdint.h>

#define CHUNKC 32
#define PRIORC 64
#define POSEC 512
#define PREDC 128
#define NB 2048
#define K1 (CHUNKC*POSEC)   // 16384
#define KS 8                // split-K factor (bf16 partials)
#define KCH (K1/KS)         // 2048

typedef __attribute__((ext_vector_type(8))) short bf16x8;
typedef __attribute__((ext_vector_type(8))) unsigned short u16x8;
typedef __attribute__((ext_vector_type(4))) float f32x4;
typedef __attribute__((ext_vector_type(4))) float f4v;

__device__ __forceinline__ unsigned short f2b(float f) {
    union { float f; unsigned int u; } x; x.f = f;
    unsigned int r = x.u + 0x7fffu + ((x.u >> 16) & 1u);
    return (unsigned short)(r >> 16);
}
__device__ __forceinline__ float b2f(unsigned short u) {
    union { unsigned int i; float f; } x; x.i = ((unsigned int)u) << 16; return x.f;
}
// f32 -> bf16 (RNE) via HIP intrinsic; compiler pairs these into v_cvt_pk_bf16_f32
__device__ __forceinline__ unsigned short cf(float f) {
    __hip_bfloat16 h = __float2bfloat16(f);
    union { __hip_bfloat16 h; unsigned short u; } x; x.h = h; return x.u;
}

__device__ __forceinline__ void gload_lds16(const void* g, void* l) {
    __builtin_amdgcn_global_load_lds(
        (const __attribute__((address_space(1))) unsigned int*)g,
        (__attribute__((address_space(3))) unsigned int*)l, 16, 0, 0);
}

// ---------------- cvt_w: W1, W2 -> bf16 (x-slice cvt eliminated) ----------------
#define W1N4  2097152   // 512*16384/4
#define W2N4  65536     // 512*512/4
__global__ __launch_bounds__(256) void cvt_w_kernel(const float4* __restrict__ W1,
                                                    const float4* __restrict__ W2,
                                                    ushort4* __restrict__ w1b,
                                                    ushort4* __restrict__ w2b) {
    const int64_t n = W1N4 + W2N4;
    const int64_t stride = (int64_t)gridDim.x * blockDim.x;
    for (int64_t i = (int64_t)blockIdx.x * blockDim.x + threadIdx.x; i < n; i += stride) {
        float4 v; ushort4* dst;
        if (i < W1N4) { v = W1[i]; dst = w1b + i; }
        else          { v = W2[i - W1N4]; dst = w2b + (i - W1N4); }
        *dst = make_ushort4(f2b(v.x), f2b(v.y), f2b(v.z), f2b(v.w));
    }
}

// ---------------- GEMM1: bf16 partials of x @ W1^T, A read DIRECTLY from init f32 ----------------
// BM=128, BN=256, BK=64, 8 waves (2x4; wave owns 64x64). A staged as f32 via
// gload_lds (raw 16B copy), converted f32->bf16 on the LDS->reg read. B staged
// bf16 (R9-proven path). 2-phase dbuf (128 KB LDS), T2 XOR-swizzle both operands:
//   A: 16 slots/row of 16B, phys_slot = logical_slot ^ (row&15) (src pre-swizzled)
//   B: 8 slots/row, phys = logical ^ (row&7)                    (src pre-swizzled)
// grid = 16mt * 2nt * 8ks = 256 blocks; XCD swizzle -> each XCD owns one ks layer.
__global__ __launch_bounds__(512) void gemm1_kernel(const float* __restrict__ init,
                                                    const ushort* __restrict__ w1b,
                                                    ushort* __restrict__ part) {
    __shared__ float  As[2][128][64];   // 2 x 32 KB f32
    __shared__ ushort Bs[2][256][64];   // 2 x 32 KB bf16
    const int t = threadIdx.x;
    const int l = t & 63, wid = t >> 6;
    const int wr = wid >> 2, wc = wid & 3;          // wave owns rows wr*64..+64, cols wc*64..+64
    const int orig = (blockIdx.x & 7) * 32 + (blockIdx.x >> 3);
    const int mt = orig & 15, nt = (orig >> 4) & 1, ks = orig >> 5;
    const int NIT = KCH / 64;                       // 32

    f32x4 acc[4][4] = {};

    // A source: x[b][k] = init[b*32768 + 16384 + k]
    const float*  aG = init + (int64_t)(mt * 128) * 32768 + 16384 + ks * KCH;
    const ushort* bG = w1b + (int64_t)(nt * 256) * K1 + ks * KCH;

    // A staging: issue i covers rows i*32..+32; lane t -> row (t>>4), phys slot (t&15)
    const int arow  = t >> 4;
    const int aslot = (t & 15) ^ ((t >> 4) & 15);   // pre-swizzled source slot
    // B staging: issue i covers rows i*64..+64; lane t -> row (t>>3), phys slot (t&7)
    const int brow = t >> 3;
    const int bcol = ((t & 7) ^ ((t >> 3) & 7)) * 8;

    const int fr = l & 15, fq = l >> 4;
    const int cxB = fr & 7;

    // prologue: stage tile 0 into buffer 0
#pragma unroll
    for (int i = 0; i < 4; ++i) {
        gload_lds16(aG + (int64_t)(i * 32 + arow) * 32768 + aslot * 4,
                    (char*)&As[0][0][0] + i * 8192 + wid * 1024);
        gload_lds16(bG + (int64_t)(i * 64 + brow) * K1 + bcol,
                    (char*)&Bs[0][0][0] + i * 8192 + wid * 1024);
    }

    for (int it = 0; it < NIT; ++it) {
        const int cur = it & 1;
        __syncthreads();    // drains buf[cur]'s loads (one iteration of cover)
        if (it + 1 < NIT) {
            const int nxt = cur ^ 1;
            const int k0 = (it + 1) * 64;
#pragma unroll
            for (int i = 0; i < 4; ++i) {
                gload_lds16(aG + (int64_t)(i * 32 + arow) * 32768 + k0 + aslot * 4,
                            (char*)&As[nxt][0][0] + i * 8192 + wid * 1024);
                gload_lds16(bG + (int64_t)(i * 64 + brow) * K1 + k0 + bcol,
                            (char*)&Bs[nxt][0][0] + i * 8192 + wid * 1024);
            }
        }
#pragma unroll
        for (int k2 = 0; k2 < 2; ++k2) {
            bf16x8 a[4], b[4];
            const int s0 = k2 * 8 + fq * 2;         // logical 16B-slot of 8-float group
#pragma unroll
            for (int m = 0; m < 4; ++m) {
                const int r = wr * 64 + m * 16 + fr;        // r&15 == fr
                f32x4 va = *(const f32x4*)&As[cur][r][((s0    ) ^ fr) * 4];
                f32x4 vb = *(const f32x4*)&As[cur][r][((s0 + 1) ^ fr) * 4];
                u16x8 w;
                w[0] = cf(va[0]); w[1] = cf(va[1]); w[2] = cf(va[2]); w[3] = cf(va[3]);
                w[4] = cf(vb[0]); w[5] = cf(vb[1]); w[6] = cf(vb[2]); w[7] = cf(vb[3]);
                union { u16x8 u; bf16x8 b; } cvtu; cvtu.u = w;
                a[m] = cvtu.b;
            }
            const int cs = ((k2 * 4 + fq) ^ cxB) * 8;
#pragma unroll
            for (int n = 0; n < 4; ++n)
                b[n] = *(const bf16x8*)&Bs[cur][wc * 64 + n * 16 + fr][cs];
#pragma unroll
            for (int m = 0; m < 4; ++m)
#pragma unroll
                for (int n = 0; n < 4; ++n)
                    acc[m][n] = __builtin_amdgcn_mfma_f32_16x16x32_bf16(a[m], b[n], acc[m][n], 0, 0, 0);
        }
    }

    ushort* P = part + (int64_t)ks * NB * POSEC;
    const int mbase = mt * 128 + wr * 64, nbase = nt * 256 + wc * 64;
#pragma unroll
    for (int m = 0; m < 4; ++m)
#pragma unroll
        for (int n = 0; n < 4; ++n) {
            int row0 = mbase + m * 16 + fq * 4;
            int col  = nbase + n * 16 + fr;
#pragma unroll
            for (int r = 0; r < 4; ++r)
                P[(int64_t)(row0 + r) * POSEC + col] = f2b(acc[m][n][r]);
        }
}

// ---------------- reduce: A2 = bf16(sum_ks bf16part + b1) ----------------
__global__ __launch_bounds__(256) void reduce_kernel(const ushort* __restrict__ part,
                                                     const float* __restrict__ b1,
                                                     u16x8* __restrict__ A2) {
    const int gid = blockIdx.x * 256 + threadIdx.x;     // 131072 threads, 8 elems each
    const int64_t e0 = (int64_t)gid * 8;
    float s[8] = {};
#pragma unroll
    for (int k = 0; k < KS; ++k) {
        u16x8 p = *(const u16x8*)(part + (int64_t)k * (NB * POSEC) + e0);
#pragma unroll
        for (int j = 0; j < 8; ++j) s[j] += b2f(p[j]);
    }
    const int col = (int)(e0 & 511);
    f4v b0 = *(const f4v*)&b1[col];
    f4v b4 = *(const f4v*)&b1[col + 4];
    u16x8 o;
#pragma unroll
    for (int j = 0; j < 4; ++j) { o[j] = f2b(s[j] + b0[j]); o[j+4] = f2b(s[j+4] + b4[j]); }
    A2[gid] = o;
}

// ---------------- GEMM2: mem = A2 @ W2b^T + b2 (R9-proven, swizzled) ----------------
__global__ __launch_bounds__(256) void gemm2_kernel(const ushort* __restrict__ A2,
                                                    const ushort* __restrict__ w2b,
                                                    const float* __restrict__ b2,
                                                    float* __restrict__ mem) {
    __shared__ ushort As[64][64];
    __shared__ ushort Bs[64][64];
    const int t = threadIdx.x;
    const int l = t & 63, wid = t >> 6;
    const int wr = wid >> 1, wc = wid & 1;
    const int mt = blockIdx.x >> 3, nt = blockIdx.x & 7;

    f32x4 acc[2][2] = {};
    const ushort* aG = A2  + (int64_t)(mt * 64) * POSEC;
    const ushort* bG = w2b + (int64_t)(nt * 64) * POSEC;
    const int srow = t >> 3;
    const int scol = (((t & 7) ^ ((t >> 3) & 7))) * 8;
    const int fr = l & 15, fq = l >> 4;
    const int cx = fr & 7;

    for (int k0 = 0; k0 < POSEC; k0 += 64) {
#pragma unroll
        for (int i = 0; i < 2; ++i) {
            gload_lds16(aG + (int64_t)(i * 32 + srow) * POSEC + k0 + scol,
                        (char*)&As[0][0] + i * 4096 + wid * 1024);
            gload_lds16(bG + (int64_t)(i * 32 + srow) * POSEC + k0 + scol,
                        (char*)&Bs[0][0] + i * 4096 + wid * 1024);
        }
        __syncthreads();
#pragma unroll
        for (int k2 = 0; k2 < 2; ++k2) {
            const int cs = ((k2 * 4 + fq) ^ cx) * 8;
            bf16x8 a[2], b[2];
#pragma unroll
            for (int m = 0; m < 2; ++m)
                a[m] = *(const bf16x8*)&As[wr * 32 + m * 16 + fr][cs];
#pragma unroll
            for (int n = 0; n < 2; ++n)
                b[n] = *(const bf16x8*)&Bs[wc * 32 + n * 16 + fr][cs];
#pragma unroll
            for (int m = 0; m < 2; ++m)
#pragma unroll
                for (int n = 0; n < 2; ++n)
                    acc[m][n] = __builtin_amdgcn_mfma_f32_16x16x32_bf16(a[m], b[n], acc[m][n], 0, 0, 0);
        }
        __syncthreads();
    }

    const int mbase = mt * 64 + wr * 32, nbase = nt * 64 + wc * 32;
#pragma unroll
    for (int m = 0; m < 2; ++m)
#pragma unroll
        for (int n = 0; n < 2; ++n) {
            int row0 = mbase + m * 16 + fq * 4;
            int col  = nbase + n * 16 + fr;
            float bias = b2[col];
#pragma unroll
            for (int r = 0; r < 4; ++r)
                mem[(int64_t)(row0 + r) * POSEC + col] = acc[m][n][r] + bias;
        }
}

// ---------------- score + sigmoid + blend + copy ----------------
__global__ __launch_bounds__(256) void blend_kernel(const float* __restrict__ pred,
                                                    const float* __restrict__ mem,
                                                    float* __restrict__ out) {
    const int b = blockIdx.x;
    const int t = threadIdx.x;
    __shared__ float sm[POSEC];
    __shared__ float sg[CHUNKC];

    sm[t]       = mem[(int64_t)b * POSEC + t];
    sm[t + 256] = mem[(int64_t)b * POSEC + 256 + t];
    __syncthreads();

    const int l = t & 63, wid = t >> 6;
    const float4* sm4 = (const float4*)sm;
    const float4* p4 = (const float4*)pred + (int64_t)b * 16384;
    float4* o4 = (float4*)out + (int64_t)b * 16384;

#pragma unroll
    for (int ci = 0; ci < 8; ++ci) {
        int c = wid * 8 + ci;
        float4 h0 = p4[c * 128 + l * 2];
        float4 h1 = p4[c * 128 + l * 2 + 1];
        float4 m0 = sm4[l * 2];
        float4 m1 = sm4[l * 2 + 1];
        float s = h0.x * m0.x + h0.y * m0.y + h0.z * m0.z + h0.w * m0.w
                + h1.x * m1.x + h1.y * m1.y + h1.z * m1.z + h1.w * m1.w;
#pragma unroll
        for (int o = 32; o; o >>= 1) s += __shfl_xor(s, o);
        if (l == 0) sg[c] = 1.0f / (1.0f + expf(-s));
    }
    __syncthreads();

#pragma unroll
    for (int i = 0; i < 16; ++i) {
        int idx = i * 256 + t;
        int row = idx >> 7, c4 = idx & 127;
        float g = sg[row];
        float4 h = p4[idx];
        float4 m = sm4[c4];
        float4 r;
        r.x = g * h.x + (1.0f - g) * m.x;
        r.y = g * h.y + (1.0f - g) * m.y;
        r.z = g * h.z + (1.0f - g) * m.z;
        r.w = g * h.w + (1.0f - g) * m.w;
        o4[idx] = r;
    }
#pragma unroll
    for (int i = 0; i < 48; ++i) {
        int idx = 4096 + i * 256 + t;
        f4v h = __builtin_nontemporal_load((const f4v*)p4 + idx);
        __builtin_nontemporal_store(h, (f4v*)o4 + idx);
    }
}

// ---------------- launch ----------------

extern "C" void kernel_launch(void* const* d_in, const int* in_sizes, int n_in,
                              void* d_out, int out_size, void* d_ws, size_t ws_size,
                              hipStream_t stream) {
    const float* init = (const float*)d_in[0];
    const float* pred = (const float*)d_in[1];
    const float* W1   = (const float*)d_in[2];
    const float* b1   = (const float*)d_in[3];
    const float* W2   = (const float*)d_in[4];
    const float* b2   = (const float*)d_in[5];
    float* out = (float*)d_out;

    char* ws = (char*)d_ws;
    ushort* w1b  = (ushort*)(ws);                       // 16777216 B
    ushort* w2b  = (ushort*)(ws + 16777216);            //   524288 B
    ushort* part = (ushort*)(ws + 17301504);            // 16777216 B (8 x 2048x512 bf16)
    ushort* A2   = (ushort*)(ws + 34078720);            //  2097152 B
    float*  mem  = (float*) (ws + 36175872);            //  4194304 B
    // total 40,370,176 B

    cvt_w_kernel<<<1024, 256, 0, stream>>>((const float4*)W1, (const float4*)W2,
                                           (ushort4*)w1b, (ushort4*)w2b);
    gemm1_kernel<<<256, 512, 0, stream>>>(init, w1b, part);
    reduce_kernel<<<512, 256, 0, stream>>>(part, b1, (u16x8*)A2);
    gemm2_kernel<<<256, 256, 0, stream>>>(A2, w2b, b2, mem);
    blend_kernel<<<NB, 256, 0, stream>>>(pred, mem, out);
}